// Round 6
// baseline (260.087 us; speedup 1.0000x reference)
//
#include <hip/hip_runtime.h>

#define WIDTH  1024
#define HEIGHT 1024
#define R      2            // rows computed per block; HEIGHT % R == 0

typedef float vfloat4 __attribute__((ext_vector_type(4)));
typedef __attribute__((address_space(3))) void       lds_void;
typedef __attribute__((address_space(1))) const void gbl_void;

__global__ __launch_bounds__(256) void fdtd_kernel(
    const float* __restrict__ u1,
    const float* __restrict__ u0,
    const float* __restrict__ j2,
    const float* __restrict__ j0,
    float* __restrict__ out,
    int chunk)                              // gridDim.x / 8 (0 => no swizzle)
{
    // 10 rows: [0..3]=u1(up-halo,r0,r1,dn-halo)  [4..5]=u0  [6..7]=j2  [8..9]=j0
    __shared__ float lds[10 * WIDTH];       // 40 KiB -> 4 blocks/CU

    const int bid = blockIdx.x;
    const int swz = chunk ? ((bid & 7) * chunk + (bid >> 3)) : bid;

    const int y0  = swz * R;                // first computed global row
    const int iy  = y0 & (HEIGHT - 1);      // row within image (blocks never straddle images)
    const int tid = threadIdx.x;
    const int wid = tid >> 6;               // wave id 0..3
    const long base = (long)y0 * WIDTH;     // float index of block's first row

    // clamped (always in-bounds) halo rows + 0/1 masks — branch-free
    const long  upRow  = (iy > 0)          ? base - WIDTH            : base;
    const long  dnRow  = (iy + R < HEIGHT) ? base + (long)R * WIDTH  : base + (long)(R - 1) * WIDTH;
    const float upMask = (iy > 0)          ? 1.0f : 0.0f;
    const float dnMask = (iy + R < HEIGHT) ? 1.0f : 0.0f;

    // ---- stage 10 rows via async global->LDS DMA: no dest VGPRs, nothing to re-batch.
    // Each thread issues 10 loads back-to-back; vmcnt tracks them; 40 KB/block in flight.
    const int goff = tid << 2;              // this thread's 16 B chunk within a row
    float* const lwave = lds + (wid << 8);  // wave-uniform LDS base (+wid*1 KiB); lanes add lane*16 B

    #define STAGE(grow, lrow)                                                       \
        __builtin_amdgcn_global_load_lds((gbl_void*)((grow) + goff),                \
                                         (lds_void*)(lwave + (lrow) * WIDTH),       \
                                         16, 0, 0)
    STAGE(u1 + upRow,        0);
    STAGE(u1 + base,         1);
    STAGE(u1 + base + WIDTH, 2);
    STAGE(u1 + dnRow,        3);
    STAGE(u0 + base,         4);
    STAGE(u0 + base + WIDTH, 5);
    STAGE(j2 + base,         6);
    STAGE(j2 + base + WIDTH, 7);
    STAGE(j0 + base,         8);
    STAGE(j0 + base + WIDTH, 9);
    #undef STAGE

    __syncthreads();                        // emits s_waitcnt vmcnt(0) + s_barrier

    // ---- compute from LDS (x-edges read directly from LDS, clamped+masked) ----
    const int   x0     = tid << 2;
    const int   lfi    = (x0 > 0)         ? x0 - 1 : 0;
    const int   rti    = (x0 + 4 < WIDTH) ? x0 + 4 : WIDTH - 1;
    const float lfMask = (x0 > 0)         ? 1.0f : 0.0f;
    const float rtMask = (x0 + 4 < WIDTH) ? 1.0f : 0.0f;

#pragma unroll
    for (int r = 0; r < R; ++r) {
        vfloat4 up = *(const vfloat4*)(lds + (r    ) * WIDTH + x0);
        vfloat4 ce = *(const vfloat4*)(lds + (r + 1) * WIDTH + x0);
        vfloat4 dn = *(const vfloat4*)(lds + (r + 2) * WIDTH + x0);
        if (r == 0)     up *= upMask;       // top halo garbage when iy==0
        if (r == R - 1) dn *= dnMask;       // bottom halo garbage when iy==HEIGHT-R

        const float lfv = lds[(r + 1) * WIDTH + lfi] * lfMask;
        const float rtv = lds[(r + 1) * WIDTH + rti] * rtMask;

        const vfloat4 a0 = *(const vfloat4*)(lds + (4 + r) * WIDTH + x0);
        const vfloat4 v2 = *(const vfloat4*)(lds + (6 + r) * WIDTH + x0);
        const vfloat4 v0 = *(const vfloat4*)(lds + (8 + r) * WIDTH + x0);

        vfloat4 o;
        o.x = 2.0f * ce.x - a0.x + 0.25f * (up.x + dn.x + lfv  + ce.y - 4.0f * ce.x)
            - 0.0025f * (v2.x - v0.x);
        o.y = 2.0f * ce.y - a0.y + 0.25f * (up.y + dn.y + ce.x + ce.z - 4.0f * ce.y)
            - 0.0025f * (v2.y - v0.y);
        o.z = 2.0f * ce.z - a0.z + 0.25f * (up.z + dn.z + ce.y + ce.w - 4.0f * ce.z)
            - 0.0025f * (v2.z - v0.z);
        o.w = 2.0f * ce.w - a0.w + 0.25f * (up.w + dn.w + ce.z + rtv  - 4.0f * ce.w)
            - 0.0025f * (v2.w - v0.w);
        __builtin_nontemporal_store(o, (vfloat4*)(out + base + (long)r * WIDTH + x0));
    }
}

extern "C" void kernel_launch(void* const* d_in, const int* in_sizes, int n_in,
                              void* d_out, int out_size, void* d_ws, size_t ws_size,
                              hipStream_t stream) {
    const float* u1 = (const float*)d_in[0];
    const float* u0 = (const float*)d_in[1];
    const float* j2 = (const float*)d_in[2];
    const float* j0 = (const float*)d_in[3];
    float* out = (float*)d_out;

    const int nrows   = out_size / WIDTH;   // B*H = 16384 (out_size is element count)
    const int nblocks = nrows / R;          // 8192
    const int chunk   = (nblocks % 8 == 0) ? (nblocks >> 3) : 0;

    dim3 block(WIDTH / 4);                  // 256 threads: one full row per block-row
    dim3 grid(nblocks);
    fdtd_kernel<<<grid, block, 0, stream>>>(u1, u0, j2, j0, out, chunk);
}

// Round 7
// 250.364 us; speedup vs baseline: 1.0388x; 1.0388x over previous
//
#include <hip/hip_runtime.h>

#define WIDTH  1024
#define HEIGHT 1024
#define R      4            // rows per block; HEIGHT % R == 0 so blocks never straddle images

typedef float vfloat4 __attribute__((ext_vector_type(4)));

__global__ __launch_bounds__(256, 2) void fdtd_kernel(   // min 2 waves/EU -> 256 VGPR cap
    const float* __restrict__ u1,
    const float* __restrict__ u0,
    const float* __restrict__ j2,
    const float* __restrict__ j0,
    float* __restrict__ out,
    int chunk)                              // gridDim.x / 8 (0 => no swizzle)
{
    // XCD-aware chunked swizzle: consecutive row-blocks share an XCD's L2.
    const int bid = blockIdx.x;
    const int swz = chunk ? ((bid & 7) * chunk + (bid >> 3)) : bid;

    const int y0 = swz * R;                 // first computed global row
    const int iy = y0 & (HEIGHT - 1);       // row within image (block fully inside one image)
    const int x0 = threadIdx.x << 2;        // 4 floats/thread, full 1024-wide row per block
    const long base = (long)y0 * WIDTH + x0;

    // ---- branch-free halo addressing: clamped (in-bounds) offsets + 0/1 masks ----
    const long  upOff  = (iy > 0)          ? -(long)WIDTH     : 0;
    const long  dnOff  = (iy + R < HEIGHT) ? (long)R * WIDTH  : (long)(R - 1) * WIDTH;
    const float upMask = (iy > 0)          ? 1.0f : 0.0f;
    const float dnMask = (iy + R < HEIGHT) ? 1.0f : 0.0f;
    const long  lfOff  = (x0 > 0)          ? -1L : 0L;
    const long  rtOff  = (x0 + 4 < WIDTH)  ?  4L : 3L;
    const float lfMask = (x0 > 0)          ? 1.0f : 0.0f;
    const float rtMask = (x0 + 4 < WIDTH)  ? 1.0f : 0.0f;

    // ---- phase 1: issue ALL loads (one basic block, every load unconditional) ----
    vfloat4 ctop, c[R], cbot, a0[R], v2[R], v0[R];
    float lf[R], rt[R];

    ctop = *(const vfloat4*)(u1 + base + upOff);
#pragma unroll
    for (int r = 0; r < R; ++r)
        c[r] = *(const vfloat4*)(u1 + base + (long)r * WIDTH);
    cbot = *(const vfloat4*)(u1 + base + dnOff);

#pragma unroll
    for (int r = 0; r < R; ++r) {
        const long b = base + (long)r * WIDTH;
        lf[r] = u1[b + lfOff];              // L1 hit (same rows as c[r])
        rt[r] = u1[b + rtOff];
        a0[r] = __builtin_nontemporal_load((const vfloat4*)(u0 + b));
        v2[r] = __builtin_nontemporal_load((const vfloat4*)(j2 + b));
        v0[r] = __builtin_nontemporal_load((const vfloat4*)(j0 + b));
    }

    // ---- liveness pin: an opaque consumer of ALL 26 load results.
    // RA cannot recycle any of these registers before this point, so all ~26
    // loads must be issued back-to-back with ONE waitcnt drain -> per-wave
    // outstanding window 8 -> 26 loads (~19 KB). This is the lever R3/R5
    // failed to engage (VGPR stayed 44/48; must jump to >=100 now).
    asm volatile(""
        : "+v"(ctop), "+v"(c[0]), "+v"(c[1]), "+v"(c[2]), "+v"(c[3]), "+v"(cbot),
          "+v"(a0[0]), "+v"(a0[1]), "+v"(a0[2]), "+v"(a0[3]),
          "+v"(v2[0]), "+v"(v2[1]), "+v"(v2[2]), "+v"(v2[3]),
          "+v"(v0[0]), "+v"(v0[1]), "+v"(v0[2]), "+v"(v0[3]),
          "+v"(lf[0]), "+v"(lf[1]), "+v"(lf[2]), "+v"(lf[3]),
          "+v"(rt[0]), "+v"(rt[1]), "+v"(rt[2]), "+v"(rt[3]));

    // ---- phase 2: compute + store ----
#pragma unroll
    for (int r = 0; r < R; ++r) {
        const vfloat4 up = (r == 0)     ? (vfloat4)(ctop * upMask) : c[r - 1];
        const vfloat4 dn = (r == R - 1) ? (vfloat4)(cbot * dnMask) : c[r + 1];
        const vfloat4 ce = c[r];
        const float lfv = lf[r] * lfMask;
        const float rtv = rt[r] * rtMask;

        vfloat4 o;
        o.x = 2.0f * ce.x - a0[r].x + 0.25f * (up.x + dn.x + lfv  + ce.y - 4.0f * ce.x)
            - 0.0025f * (v2[r].x - v0[r].x);
        o.y = 2.0f * ce.y - a0[r].y + 0.25f * (up.y + dn.y + ce.x + ce.z - 4.0f * ce.y)
            - 0.0025f * (v2[r].y - v0[r].y);
        o.z = 2.0f * ce.z - a0[r].z + 0.25f * (up.z + dn.z + ce.y + ce.w - 4.0f * ce.z)
            - 0.0025f * (v2[r].z - v0[r].z);
        o.w = 2.0f * ce.w - a0[r].w + 0.25f * (up.w + dn.w + ce.z + rtv  - 4.0f * ce.w)
            - 0.0025f * (v2[r].w - v0[r].w);
        __builtin_nontemporal_store(o, (vfloat4*)(out + base + (long)r * WIDTH));
    }
}

extern "C" void kernel_launch(void* const* d_in, const int* in_sizes, int n_in,
                              void* d_out, int out_size, void* d_ws, size_t ws_size,
                              hipStream_t stream) {
    const float* u1 = (const float*)d_in[0];
    const float* u0 = (const float*)d_in[1];
    const float* j2 = (const float*)d_in[2];
    const float* j0 = (const float*)d_in[3];
    float* out = (float*)d_out;

    const int nrows   = out_size / WIDTH;   // B*H = 16384 (out_size is element count)
    const int nblocks = nrows / R;          // 4096
    const int chunk   = (nblocks % 8 == 0) ? (nblocks >> 3) : 0;

    dim3 block(WIDTH / 4);                  // 256 threads: one full row per block-row
    dim3 grid(nblocks);
    fdtd_kernel<<<grid, block, 0, stream>>>(u1, u0, j2, j0, out, chunk);
}